// Round 12
// baseline (865.215 us; speedup 1.0000x reference)
//
#include <hip/hip_runtime.h>
#include <hip/hip_bf16.h>

// QuantizedLinear: out[m,o] = sum_k x[m,k] * (q[o,k]-z[o,g])*s[o,g] + b[o]
// M=8192, K=4096, N=11008. Pass1 (fused): cvt x->bf16 + dequant W->bf16.
// Pass2: 256x256 bf16 GEMM, ONE barrier per K-tile, single post-barrier stage
// slot: tile t stages ALL of (t+2) into cur_t's buffer (its readers drained at
// BAR(t)); the pre-BAR wait at t+1 drains loads issued a FULL tile earlier
// (~2500 cyc cover >> 900 cyc HBM) -> zero-cost vmcnt(0). All 24 frag reads
// pre-barrier (VGPR ~245), 64-MFMA monolith post-barrier with no lgkm deps;
// stage-writes land during the MFMA window (LDS pipe otherwise idle).
//   tile t: [24 reads cur][s_waitcnt vmcnt(0) lgkmcnt(0)][BAR]
//           [stage ALL t+2 -> cur][64 MFMA]
// T1 XCD swizzle, T2 LDS swizzle (inverse-swizzled global source), T5 setprio.

#define K_DIM 4096
#define N_DIM 11008
#define M_DIM 8192
#define NGRP 32

typedef __bf16 bf16x8 __attribute__((ext_vector_type(8)));
typedef float f32x4 __attribute__((ext_vector_type(4)));
typedef unsigned short u16x8 __attribute__((ext_vector_type(8)));

__device__ __forceinline__ unsigned short f2bf(float f) {
  unsigned u = __builtin_bit_cast(unsigned, f);
  return (unsigned short)((u + 0x7FFFu + ((u >> 16) & 1u)) >> 16);  // RNE
}

__device__ __forceinline__ void gload_lds16(const void* g, void* l) {
  __builtin_amdgcn_global_load_lds(
      (const __attribute__((address_space(1))) unsigned int*)(unsigned long long)g,
      (__attribute__((address_space(3))) unsigned int*)(unsigned int)(unsigned long long)l,
      16, 0, 0);
}

// ---- pass 1 (fused): blocks [0,16384) cvt x; [16384, 38400) dequant W ----
__global__ __launch_bounds__(256) void prep_kernel(const float4* __restrict__ x4,
                                                   const int4* __restrict__ q4,
                                                   const float* __restrict__ scales,
                                                   const float* __restrict__ zeros,
                                                   u16x8* __restrict__ xb,
                                                   u16x8* __restrict__ wb) {
  const int bid = blockIdx.x;
  if (bid < 16384) {
    int i = bid * 256 + threadIdx.x;
    float4 a = x4[2 * i], b = x4[2 * i + 1];
    u16x8 r;
    r[0] = f2bf(a.x); r[1] = f2bf(a.y); r[2] = f2bf(a.z); r[3] = f2bf(a.w);
    r[4] = f2bf(b.x); r[5] = f2bf(b.y); r[6] = f2bf(b.z); r[7] = f2bf(b.w);
    xb[i] = r;
  } else {
    int t = (bid - 16384) * 256 + threadIdx.x;
    int o = t >> 9;
    int j8 = t & 511;
    int g = j8 >> 4;
    float s = scales[o * NGRP + g];
    float z = zeros[o * NGRP + g];
    float nzs = -z * s;
    int4 qa = q4[2 * t], qb = q4[2 * t + 1];
    u16x8 r;
    r[0] = f2bf(fmaf((float)qa.x, s, nzs));
    r[1] = f2bf(fmaf((float)qa.y, s, nzs));
    r[2] = f2bf(fmaf((float)qa.z, s, nzs));
    r[3] = f2bf(fmaf((float)qa.w, s, nzs));
    r[4] = f2bf(fmaf((float)qb.x, s, nzs));
    r[5] = f2bf(fmaf((float)qb.y, s, nzs));
    r[6] = f2bf(fmaf((float)qb.z, s, nzs));
    r[7] = f2bf(fmaf((float)qb.w, s, nzs));
    wb[t] = r;
  }
}

// ---- pass 2: 256x256 bf16 GEMM, 1 barrier / K-tile, full-tile post-BAR stage ----
#define BAR() __builtin_amdgcn_s_barrier()
#define SCHED0() __builtin_amdgcn_sched_barrier(0)

__global__ __launch_bounds__(512, 2) void gemm_kernel(const unsigned short* __restrict__ A,
                                                      const unsigned short* __restrict__ B,
                                                      const float* __restrict__ bias,
                                                      float* __restrict__ C) {
  extern __shared__ unsigned short smem[];
  unsigned short* sAb = smem;           // [2 buf][2 half][8192]
  unsigned short* sBb = smem + 32768;

  const int bid = blockIdx.x;
  // T1: 1376 blocks, 1376 % 8 == 0 -> simple bijective XCD swizzle.
  const int swz = (bid & 7) * 172 + (bid >> 3);
  const int tm = swz / 43, tn = swz % 43;

  const int tid = threadIdx.x;
  const int w = tid >> 6, l = tid & 63;
  const int wr = w >> 2, wc = w & 3;

  const int dsto = w * 512 + l * 8;            // LDS elem offset (wave base + lane*16B)
  const int gs = (l & 7) ^ (l >> 3);           // inverse T2 swizzle on global source slot
  const unsigned short* gA = A + (size_t)(tm * 256 + (tid >> 3)) * K_DIM + gs * 8;
  const unsigned short* gB = B + (size_t)(tn * 256 + (tid >> 3)) * K_DIM + gs * 8;

#define STG_A(tt, h, dst)                                                       \
  do {                                                                          \
    const unsigned short* _s = gA + (size_t)(h) * 128 * K_DIM + (tt) * 64;      \
    gload_lds16(_s, (dst) + dsto);                                              \
    gload_lds16(_s + 64 * K_DIM, (dst) + 4096 + dsto);                          \
  } while (0)
#define STG_B(tt, h, dst)                                                       \
  do {                                                                          \
    const unsigned short* _s = gB + (size_t)(h) * 128 * K_DIM + (tt) * 64;      \
    gload_lds16(_s, (dst) + dsto);                                              \
    gload_lds16(_s + 64 * K_DIM, (dst) + 4096 + dsto);                          \
  } while (0)

  // fragment read coords (16x16x32: lane row=l&15, k-chunk=l>>4, swizzled slots)
  const int fr = l & 15, sb = l >> 4, x7 = l & 7;
  const int abase = (wr * 64 + fr) * 64;
  const int bbase = (wc * 32 + fr) * 64;
  const int k0 = (sb ^ x7) * 8;
  const int k1 = ((sb + 4) ^ x7) * 8;

  bf16x8 av0[4][2], av1[4][2], bva[2][2], bvb[2][2];
  f32x4 acc[8][4] = {};

#define READ_A(half, avv)                                                \
  {                                                                      \
    _Pragma("unroll") for (int m = 0; m < 4; ++m) {                      \
      avv[m][0] = *(const bf16x8*)((half) + abase + m * 1024 + k0);      \
      avv[m][1] = *(const bf16x8*)((half) + abase + m * 1024 + k1);      \
    }                                                                    \
  }
#define READ_B(half, arr)                                                \
  {                                                                      \
    _Pragma("unroll") for (int n = 0; n < 2; ++n) {                      \
      arr[n][0] = *(const bf16x8*)((half) + bbase + n * 1024 + k0);      \
      arr[n][1] = *(const bf16x8*)((half) + bbase + n * 1024 + k1);      \
    }                                                                    \
  }
#define MFMA_Q(mh, nh, arr, avv)                                                   \
  {                                                                                \
    _Pragma("unroll") for (int kk = 0; kk < 2; ++kk)                               \
    _Pragma("unroll") for (int m = 0; m < 4; ++m)                                  \
    _Pragma("unroll") for (int nn = 0; nn < 2; ++nn)                               \
      acc[(mh)*4 + m][(nh)*2 + nn] = __builtin_amdgcn_mfma_f32_16x16x32_bf16(      \
          avv[m][kk], arr[nn][kk], acc[(mh)*4 + m][(nh)*2 + nn], 0, 0, 0);         \
  }

// One K-tile: 24 reads | waitcnt(0,0) | BAR | stage ALL of t+2 -> cur | 64 MFMA.
#define TILE(tt, curA, curB, do_stage)                                   \
  {                                                                      \
    READ_A(curA, av0);                                                   \
    READ_A((curA) + 8192, av1);                                          \
    READ_B(curB, bva);                                                   \
    READ_B((curB) + 8192, bvb);                                          \
    asm volatile("s_waitcnt vmcnt(0) lgkmcnt(0)" ::: "memory");          \
    SCHED0();                                                            \
    BAR();                                                               \
    SCHED0();                                                            \
    if (do_stage) {                                                      \
      STG_A(tt + 2, 0, curA);                                            \
      STG_A(tt + 2, 1, (curA) + 8192);                                   \
      STG_B(tt + 2, 0, curB);                                            \
      STG_B(tt + 2, 1, (curB) + 8192);                                   \
    }                                                                    \
    __builtin_amdgcn_s_setprio(1);                                       \
    MFMA_Q(0, 0, bva, av0);                                              \
    MFMA_Q(0, 1, bvb, av0);                                              \
    MFMA_Q(1, 1, bvb, av1);                                              \
    MFMA_Q(1, 0, bva, av1);                                              \
    __builtin_amdgcn_s_setprio(0);                                       \
  }

  // ---- prologue: stage tile0 -> buf0, tile1 -> buf1 ----
  STG_A(0, 0, sAb);
  STG_A(0, 1, sAb + 8192);
  STG_B(0, 0, sBb);
  STG_B(0, 1, sBb + 8192);
  STG_A(1, 0, sAb + 16384);
  STG_A(1, 1, sAb + 16384 + 8192);
  STG_B(1, 0, sBb + 16384);
  STG_B(1, 1, sBb + 16384 + 8192);
  asm volatile("s_waitcnt vmcnt(8)" ::: "memory");  // tile 0 resident
  BAR();
  SCHED0();

  for (int tt = 0; tt < 32; ++tt) {
    // even tile 2*tt: cur = buf0; stage 2*tt+2 -> buf0 (skip at tt=31)
    TILE(2 * tt, sAb, sBb, (tt < 31));
    // odd tile 2*tt+1: cur = buf1; stage 2*tt+3 -> buf1 (skip at tt=31)
    TILE(2 * tt + 1, sAb + 16384, sBb + 16384, (tt < 31));
  }

  // ---- epilogue: C/D layout col=lane&15, row=(lane>>4)*4+reg ----
  const int r0 = tm * 256 + wr * 64 + sb * 4;
  const int c0 = tn * 256 + wc * 32 + fr;
#pragma unroll
  for (int n = 0; n < 4; ++n) {
    const int col = c0 + (n >> 1) * 128 + (n & 1) * 16;
    const float bv = bias[col];
#pragma unroll
    for (int mi = 0; mi < 8; ++mi) {
      const int row = r0 + (mi >> 2) * 128 + (mi & 3) * 16;
#pragma unroll
      for (int jj = 0; jj < 4; ++jj)
        C[(size_t)(row + jj) * N_DIM + col] = acc[mi][n][jj] + bv;
    }
  }
}

extern "C" void kernel_launch(void* const* d_in, const int* in_sizes, int n_in,
                              void* d_out, int out_size, void* d_ws, size_t ws_size,
                              hipStream_t stream) {
  const float* x = (const float*)d_in[0];
  const int* qw = (const int*)d_in[1];
  const float* sc = (const float*)d_in[2];
  const float* zr = (const float*)d_in[3];
  const float* bs = (const float*)d_in[4];
  float* out = (float*)d_out;

  const size_t xb_bytes = (size_t)M_DIM * K_DIM * 2;
  const size_t wb_bytes = (size_t)N_DIM * K_DIM * 2;
  if (ws_size < xb_bytes + wb_bytes) return;

  unsigned short* xb = (unsigned short*)d_ws;
  unsigned short* wb = (unsigned short*)((char*)d_ws + xb_bytes);

  (void)hipFuncSetAttribute((const void*)gemm_kernel,
                            hipFuncAttributeMaxDynamicSharedMemorySize, 131072);

  prep_kernel<<<16384 + 22016, 256, 0, stream>>>((const float4*)x, (const int4*)qw, sc, zr,
                                                 (u16x8*)xb, (u16x8*)wb);
  gemm_kernel<<<(M_DIM / 256) * (N_DIM / 256), 512, 131072, stream>>>(xb, wb, bs, out);
}

// Round 13
// 769.533 us; speedup vs baseline: 1.1243x; 1.1243x over previous
//
#include <hip/hip_runtime.h>
#include <hip/hip_bf16.h>

// QuantizedLinear: out[m,o] = sum_k x[m,k] * (q[o,k]-z[o,g])*s[o,g] + b[o]
// M=8192, K=4096, N=11008. Pass1 (fused): cvt x->bf16 + dequant W->bf16.
// Pass2: 256x256 bf16 GEMM = R10 structure (2 phases/K-tile, read|BAR|MFMA
// handshake, counted vmcnt(4), T1 XCD swizzle, T2 LDS swizzle, T5 setprio)
// with MFMA shape switched 16x16x32 -> 32x32x16 (m119: +15% matrix rate,
// half the MFMA instruction count; same LDS bytes, same register footprint).
// A-frag: row=l&31, k=(l>>5)*8; slot(ks) = (ks*2+(l>>5)) ^ (l&7) under the
// same 8-slot XOR layout. C/D: col=lane&31, row=(reg&3)+8*(reg>>2)+4*(lane>>5)
// (m74/m101-verified).

#define K_DIM 4096
#define N_DIM 11008
#define M_DIM 8192
#define NGRP 32

typedef __bf16 bf16x8 __attribute__((ext_vector_type(8)));
typedef float f32x16 __attribute__((ext_vector_type(16)));
typedef unsigned short u16x8 __attribute__((ext_vector_type(8)));

__device__ __forceinline__ unsigned short f2bf(float f) {
  unsigned u = __builtin_bit_cast(unsigned, f);
  return (unsigned short)((u + 0x7FFFu + ((u >> 16) & 1u)) >> 16);  // RNE
}

__device__ __forceinline__ void gload_lds16(const void* g, void* l) {
  __builtin_amdgcn_global_load_lds(
      (const __attribute__((address_space(1))) unsigned int*)(unsigned long long)g,
      (__attribute__((address_space(3))) unsigned int*)(unsigned int)(unsigned long long)l,
      16, 0, 0);
}

// ---- pass 1 (fused): blocks [0,16384) cvt x; [16384, 38400) dequant W ----
__global__ __launch_bounds__(256) void prep_kernel(const float4* __restrict__ x4,
                                                   const int4* __restrict__ q4,
                                                   const float* __restrict__ scales,
                                                   const float* __restrict__ zeros,
                                                   u16x8* __restrict__ xb,
                                                   u16x8* __restrict__ wb) {
  const int bid = blockIdx.x;
  if (bid < 16384) {
    int i = bid * 256 + threadIdx.x;
    float4 a = x4[2 * i], b = x4[2 * i + 1];
    u16x8 r;
    r[0] = f2bf(a.x); r[1] = f2bf(a.y); r[2] = f2bf(a.z); r[3] = f2bf(a.w);
    r[4] = f2bf(b.x); r[5] = f2bf(b.y); r[6] = f2bf(b.z); r[7] = f2bf(b.w);
    xb[i] = r;
  } else {
    int t = (bid - 16384) * 256 + threadIdx.x;
    int o = t >> 9;
    int j8 = t & 511;
    int g = j8 >> 4;
    float s = scales[o * NGRP + g];
    float z = zeros[o * NGRP + g];
    float nzs = -z * s;
    int4 qa = q4[2 * t], qb = q4[2 * t + 1];
    u16x8 r;
    r[0] = f2bf(fmaf((float)qa.x, s, nzs));
    r[1] = f2bf(fmaf((float)qa.y, s, nzs));
    r[2] = f2bf(fmaf((float)qa.z, s, nzs));
    r[3] = f2bf(fmaf((float)qa.w, s, nzs));
    r[4] = f2bf(fmaf((float)qb.x, s, nzs));
    r[5] = f2bf(fmaf((float)qb.y, s, nzs));
    r[6] = f2bf(fmaf((float)qb.z, s, nzs));
    r[7] = f2bf(fmaf((float)qb.w, s, nzs));
    wb[t] = r;
  }
}

// ---- pass 2: 256x256 bf16 GEMM, 32x32x16 MFMA, R10 sync structure ----
#define BAR() __builtin_amdgcn_s_barrier()
#define SCHED0() __builtin_amdgcn_sched_barrier(0)

__global__ __launch_bounds__(512, 2) void gemm_kernel(const unsigned short* __restrict__ A,
                                                      const unsigned short* __restrict__ B,
                                                      const float* __restrict__ bias,
                                                      float* __restrict__ C) {
  extern __shared__ unsigned short smem[];
  unsigned short* sAb = smem;           // [2 buf][2 half][8192]  (128 rows x 64 k)
  unsigned short* sBb = smem + 32768;

  const int bid = blockIdx.x;
  // T1: 1376 blocks, 1376 % 8 == 0 -> simple bijective XCD swizzle.
  const int swz = (bid & 7) * 172 + (bid >> 3);
  const int tm = swz / 43, tn = swz % 43;

  const int tid = threadIdx.x;
  const int w = tid >> 6, l = tid & 63;
  const int wr = w >> 2, wc = w & 3;

  const int dsto = w * 512 + l * 8;            // LDS elem offset (wave base + lane*16B)
  const int gs = (l & 7) ^ (l >> 3);           // inverse T2 swizzle on global source slot
  const unsigned short* gA = A + (size_t)(tm * 256 + (tid >> 3)) * K_DIM + gs * 8;
  const unsigned short* gB = B + (size_t)(tn * 256 + (tid >> 3)) * K_DIM + gs * 8;

#define STG_A(tt, h, dst)                                                       \
  do {                                                                          \
    const unsigned short* _s = gA + (size_t)(h) * 128 * K_DIM + (tt) * 64;      \
    gload_lds16(_s, (dst) + dsto);                                              \
    gload_lds16(_s + 64 * K_DIM, (dst) + 4096 + dsto);                          \
  } while (0)
#define STG_B(tt, h, dst)                                                       \
  do {                                                                          \
    const unsigned short* _s = gB + (size_t)(h) * 128 * K_DIM + (tt) * 64;      \
    gload_lds16(_s, (dst) + dsto);                                              \
    gload_lds16(_s + 64 * K_DIM, (dst) + 4096 + dsto);                          \
  } while (0)

  // 32x32x16 fragment coords: lane row/col = l&31, k-chunk = l>>5, 8 bf16/lane.
  const int l31 = l & 31, lk = l >> 5, x7 = l & 7;
  // swizzled 16B-slot index for k-slice ks: (ks*2 + lk) ^ x7  (row&7 == x7)
  const int sl0 = (0 + lk) ^ x7;
  const int sl1 = (2 + lk) ^ x7;
  const int sl2 = (4 + lk) ^ x7;
  const int sl3 = (6 + lk) ^ x7;
  const int abase = (wr * 64 + l31) * 64;  // + mf*32*64
  const int bbase = (wc * 32 + l31) * 64;

  bf16x8 avv[2][4], bv0[4], bv1[4];  // A: [mf][ks]; B: [ks]
  f32x16 acc[4][2] = {};             // [mi = ha*2+mf][hb]

#define READ_A(half)                                                       \
  {                                                                        \
    _Pragma("unroll") for (int mf = 0; mf < 2; ++mf) {                     \
      avv[mf][0] = *(const bf16x8*)((half) + abase + mf * 2048 + sl0 * 8); \
      avv[mf][1] = *(const bf16x8*)((half) + abase + mf * 2048 + sl1 * 8); \
      avv[mf][2] = *(const bf16x8*)((half) + abase + mf * 2048 + sl2 * 8); \
      avv[mf][3] = *(const bf16x8*)((half) + abase + mf * 2048 + sl3 * 8); \
    }                                                                      \
  }
#define READ_B(half, arr)                                                  \
  {                                                                        \
    arr[0] = *(const bf16x8*)((half) + bbase + sl0 * 8);                   \
    arr[1] = *(const bf16x8*)((half) + bbase + sl1 * 8);                   \
    arr[2] = *(const bf16x8*)((half) + bbase + sl2 * 8);                   \
    arr[3] = *(const bf16x8*)((half) + bbase + sl3 * 8);                   \
  }
#define MFMA_Q(ha, hb, barr)                                                        \
  {                                                                                 \
    __builtin_amdgcn_s_setprio(1);                                                  \
    _Pragma("unroll") for (int ks = 0; ks < 4; ++ks)                                \
    _Pragma("unroll") for (int mf = 0; mf < 2; ++mf)                                \
      acc[(ha)*2 + mf][hb] = __builtin_amdgcn_mfma_f32_32x32x16_bf16(               \
          avv[mf][ks], barr[ks], acc[(ha)*2 + mf][hb], 0, 0, 0);                    \
    __builtin_amdgcn_s_setprio(0);                                                  \
  }

  // ---- prologue: tile0 all 4 halves + A0(1), B1(1) into buf1 ----
  STG_A(0, 0, sAb);
  STG_A(0, 1, sAb + 8192);
  STG_B(0, 0, sBb);
  STG_B(0, 1, sBb + 8192);
  STG_A(1, 0, sAb + 16384);
  STG_B(1, 1, sBb + 16384 + 8192);
  asm volatile("s_waitcnt vmcnt(4)" ::: "memory");
  BAR();
  SCHED0();

  for (int tt = 0; tt < 32; ++tt) {
    // ======== even tile t = 2*tt (cur = buf0, nxt = buf1) ========
    // P1: reads + stages BEFORE barrier; MFMA after
    READ_A(sAb);
    READ_B(sBb, bv0);
    READ_B(sBb + 8192, bv1);
    STG_A(2 * tt + 1, 1, sAb + 16384 + 8192);
    STG_B(2 * tt + 1, 0, sBb + 16384);
    SCHED0();
    BAR();
    SCHED0();
    MFMA_Q(0, 0, bv0);
    MFMA_Q(0, 1, bv1);
    // P2
    READ_A(sAb + 8192);
    if (tt < 31) {
      STG_A(2 * tt + 2, 0, sAb);
      STG_B(2 * tt + 2, 1, sBb + 8192);
    }
    if (tt < 31) {
      asm volatile("s_waitcnt vmcnt(4)" ::: "memory");
    } else {
      asm volatile("s_waitcnt vmcnt(0)" ::: "memory");
    }
    SCHED0();
    BAR();
    SCHED0();
    MFMA_Q(1, 1, bv1);
    MFMA_Q(1, 0, bv0);

    // ======== odd tile t = 2*tt+1 (cur = buf1, nxt = buf0) ========
    READ_A(sAb + 16384);
    READ_B(sBb + 16384, bv0);
    READ_B(sBb + 16384 + 8192, bv1);
    if (tt < 31) {
      STG_A(2 * tt + 2, 1, sAb + 8192);
      STG_B(2 * tt + 2, 0, sBb);
    }
    SCHED0();
    BAR();
    SCHED0();
    MFMA_Q(0, 0, bv0);
    MFMA_Q(0, 1, bv1);
    // P2
    READ_A(sAb + 16384 + 8192);
    if (tt < 31) {
      STG_A(2 * tt + 3, 0, sAb + 16384);
      STG_B(2 * tt + 3, 1, sBb + 16384 + 8192);
    }
    if (tt < 31) {
      asm volatile("s_waitcnt vmcnt(4)" ::: "memory");
      SCHED0();
      BAR();
      SCHED0();
    }
    MFMA_Q(1, 1, bv1);
    MFMA_Q(1, 0, bv0);
  }

  // ---- epilogue: 32x32 C/D layout col=lane&31, row=(reg&3)+8*(reg>>2)+4*(lane>>5) ----
  const int r0 = tm * 256 + wr * 64 + 4 * lk;
  const int c0 = tn * 256 + wc * 32 + l31;
#pragma unroll
  for (int hb = 0; hb < 2; ++hb) {
    const int col = c0 + hb * 128;
    const float bvl = bias[col];
#pragma unroll
    for (int mi = 0; mi < 4; ++mi) {
      const int rowb = r0 + (mi >> 1) * 128 + (mi & 1) * 32;
#pragma unroll
      for (int reg = 0; reg < 16; ++reg) {
        const int row = rowb + (reg & 3) + 8 * (reg >> 2);
        C[(size_t)row * N_DIM + col] = acc[mi][hb][reg] + bvl;
      }
    }
  }
}

extern "C" void kernel_launch(void* const* d_in, const int* in_sizes, int n_in,
                              void* d_out, int out_size, void* d_ws, size_t ws_size,
                              hipStream_t stream) {
  const float* x = (const float*)d_in[0];
  const int* qw = (const int*)d_in[1];
  const float* sc = (const float*)d_in[2];
  const float* zr = (const float*)d_in[3];
  const float* bs = (const float*)d_in[4];
  float* out = (float*)d_out;

  const size_t xb_bytes = (size_t)M_DIM * K_DIM * 2;
  const size_t wb_bytes = (size_t)N_DIM * K_DIM * 2;
  if (ws_size < xb_bytes + wb_bytes) return;

  unsigned short* xb = (unsigned short*)d_ws;
  unsigned short* wb = (unsigned short*)((char*)d_ws + xb_bytes);

  (void)hipFuncSetAttribute((const void*)gemm_kernel,
                            hipFuncAttributeMaxDynamicSharedMemorySize, 131072);

  prep_kernel<<<16384 + 22016, 256, 0, stream>>>((const float4*)x, (const int4*)qw, sc, zr,
                                                 (u16x8*)xb, (u16x8*)wb);
  gemm_kernel<<<(M_DIM / 256) * (N_DIM / 256), 512, 131072, stream>>>(xb, wb, bs, out);
}

// Round 14
// 716.420 us; speedup vs baseline: 1.2077x; 1.0741x over previous
//
#include <hip/hip_runtime.h>
#include <hip/hip_bf16.h>

// QuantizedLinear: out[m,o] = sum_k x[m,k] * (q[o,k]-z[o,g])*s[o,g] + b[o]
// M=8192, K=4096, N=11008. Pass1 (fused): cvt x->bf16 + dequant W->bf16.
// Pass2: 256x256 bf16 GEMM — R10 proven structure: 2 phases/K-tile,
// read|BAR|MFMA handshake, counted vmcnt(4) never-drain, T1 XCD swizzle,
// T2 LDS swizzle (inverse-swizzled global source), T5 setprio, 16x16x32 MFMA
// (only measured conflict-free read layout: slot = (kc + sb) ^ (l&7)).
// R14: N-split tail. 1376 tiles = 5.375 rounds; last 96 tiles become two
// 256x128 half-jobs each (grid 1280 full + 192 half, fulls first). Half-jobs
// stage identically (schedule constants untouched), skip half the B-reads /
// MFMA quadrants / epilogue (block-uniform), plain-store disjoint C halves:
// no atomics, no zeroing, bit-deterministic.

#define K_DIM 4096
#define N_DIM 11008
#define M_DIM 8192
#define NGRP 32

typedef __bf16 bf16x8 __attribute__((ext_vector_type(8)));
typedef float f32x4 __attribute__((ext_vector_type(4)));
typedef unsigned short u16x8 __attribute__((ext_vector_type(8)));

__device__ __forceinline__ unsigned short f2bf(float f) {
  unsigned u = __builtin_bit_cast(unsigned, f);
  return (unsigned short)((u + 0x7FFFu + ((u >> 16) & 1u)) >> 16);  // RNE
}

__device__ __forceinline__ void gload_lds16(const void* g, void* l) {
  __builtin_amdgcn_global_load_lds(
      (const __attribute__((address_space(1))) unsigned int*)(unsigned long long)g,
      (__attribute__((address_space(3))) unsigned int*)(unsigned int)(unsigned long long)l,
      16, 0, 0);
}

// ---- pass 1 (fused): blocks [0,16384) cvt x; [16384, 38400) dequant W ----
__global__ __launch_bounds__(256) void prep_kernel(const float4* __restrict__ x4,
                                                   const int4* __restrict__ q4,
                                                   const float* __restrict__ scales,
                                                   const float* __restrict__ zeros,
                                                   u16x8* __restrict__ xb,
                                                   u16x8* __restrict__ wb) {
  const int bid = blockIdx.x;
  if (bid < 16384) {
    int i = bid * 256 + threadIdx.x;
    float4 a = x4[2 * i], b = x4[2 * i + 1];
    u16x8 r;
    r[0] = f2bf(a.x); r[1] = f2bf(a.y); r[2] = f2bf(a.z); r[3] = f2bf(a.w);
    r[4] = f2bf(b.x); r[5] = f2bf(b.y); r[6] = f2bf(b.z); r[7] = f2bf(b.w);
    xb[i] = r;
  } else {
    int t = (bid - 16384) * 256 + threadIdx.x;
    int o = t >> 9;
    int j8 = t & 511;
    int g = j8 >> 4;
    float s = scales[o * NGRP + g];
    float z = zeros[o * NGRP + g];
    float nzs = -z * s;
    int4 qa = q4[2 * t], qb = q4[2 * t + 1];
    u16x8 r;
    r[0] = f2bf(fmaf((float)qa.x, s, nzs));
    r[1] = f2bf(fmaf((float)qa.y, s, nzs));
    r[2] = f2bf(fmaf((float)qa.z, s, nzs));
    r[3] = f2bf(fmaf((float)qa.w, s, nzs));
    r[4] = f2bf(fmaf((float)qb.x, s, nzs));
    r[5] = f2bf(fmaf((float)qb.y, s, nzs));
    r[6] = f2bf(fmaf((float)qb.z, s, nzs));
    r[7] = f2bf(fmaf((float)qb.w, s, nzs));
    wb[t] = r;
  }
}

// ---- pass 2: 256x256 bf16 GEMM, 2 phases / K-tile, read|BAR|MFMA handshake ----
#define BAR() __builtin_amdgcn_s_barrier()
#define SCHED0() __builtin_amdgcn_sched_barrier(0)

__global__ __launch_bounds__(512, 2) void gemm_kernel(const unsigned short* __restrict__ A,
                                                      const unsigned short* __restrict__ B,
                                                      const float* __restrict__ bias,
                                                      float* __restrict__ C) {
  extern __shared__ unsigned short smem[];
  unsigned short* sAb = smem;           // [2 buf][2 half][8192]
  unsigned short* sBb = smem + 32768;

  // Job decode (block-uniform): j<1280 -> full tile j; else half-job on tail
  // tile 1280+(r%96), N-half nh=r/96.
  const int j = blockIdx.x;
  int tileIdx, nh;
  bool isFull;
  if (j < 1280) {
    tileIdx = j; nh = 0; isFull = true;
  } else {
    int r = j - 1280;
    tileIdx = 1280 + (r % 96);
    nh = r / 96;
    isFull = false;
  }

  // T1: 1376-tile space, %8==0 -> simple bijective XCD swizzle.
  const int swz = (tileIdx & 7) * 172 + (tileIdx >> 3);
  const int tm = swz / 43, tn = swz % 43;

  const int tid = threadIdx.x;
  const int w = tid >> 6, l = tid & 63;
  const int wr = w >> 2, wc = w & 3;

  const int dsto = w * 512 + l * 8;            // LDS elem offset (wave base + lane*16B)
  const int gs = (l & 7) ^ (l >> 3);           // inverse T2 swizzle on global source slot
  const unsigned short* gA = A + (size_t)(tm * 256 + (tid >> 3)) * K_DIM + gs * 8;
  const unsigned short* gB = B + (size_t)(tn * 256 + (tid >> 3)) * K_DIM + gs * 8;

#define STG_A(tt, h, dst)                                                       \
  do {                                                                          \
    const unsigned short* _s = gA + (size_t)(h) * 128 * K_DIM + (tt) * 64;      \
    gload_lds16(_s, (dst) + dsto);                                              \
    gload_lds16(_s + 64 * K_DIM, (dst) + 4096 + dsto);                          \
  } while (0)
#define STG_B(tt, h, dst)                                                       \
  do {                                                                          \
    const unsigned short* _s = gB + (size_t)(h) * 128 * K_DIM + (tt) * 64;      \
    gload_lds16(_s, (dst) + dsto);                                              \
    gload_lds16(_s + 64 * K_DIM, (dst) + 4096 + dsto);                          \
  } while (0)

  // fragment read coords (16x16x32: lane row=l&15, k-chunk=l>>4, swizzled slots)
  const int fr = l & 15, sb = l >> 4, x7 = l & 7;
  const int abase = (wr * 64 + fr) * 64;
  const int bbase = (wc * 32 + fr) * 64;
  const int k0 = (sb ^ x7) * 8;
  const int k1 = ((sb + 4) ^ x7) * 8;

  bf16x8 av[4][2], bva[2][2], bvb[2][2];
  f32x4 acc[8][4] = {};

#define READ_A(half)                                                     \
  {                                                                      \
    _Pragma("unroll") for (int m = 0; m < 4; ++m) {                      \
      av[m][0] = *(const bf16x8*)((half) + abase + m * 1024 + k0);       \
      av[m][1] = *(const bf16x8*)((half) + abase + m * 1024 + k1);       \
    }                                                                    \
  }
#define READ_B(half, arr)                                                \
  {                                                                      \
    _Pragma("unroll") for (int n = 0; n < 2; ++n) {                      \
      arr[n][0] = *(const bf16x8*)((half) + bbase + n * 1024 + k0);      \
      arr[n][1] = *(const bf16x8*)((half) + bbase + n * 1024 + k1);      \
    }                                                                    \
  }
#define MFMA_Q(mh, nhq, arr)                                                       \
  {                                                                                \
    __builtin_amdgcn_s_setprio(1);                                                 \
    _Pragma("unroll") for (int kk = 0; kk < 2; ++kk)                               \
    _Pragma("unroll") for (int m = 0; m < 4; ++m)                                  \
    _Pragma("unroll") for (int nn = 0; nn < 2; ++nn)                               \
      acc[(mh)*4 + m][(nhq)*2 + nn] = __builtin_amdgcn_mfma_f32_16x16x32_bf16(     \
          av[m][kk], arr[nn][kk], acc[(mh)*4 + m][(nhq)*2 + nn], 0, 0, 0);         \
    __builtin_amdgcn_s_setprio(0);                                                 \
  }

  const bool doB0 = isFull || (nh == 0);
  const bool doB1 = isFull || (nh == 1);

  // ---- prologue: tile0 all 4 halves + A0(1), B1(1) into buf1 ----
  STG_A(0, 0, sAb);
  STG_A(0, 1, sAb + 8192);
  STG_B(0, 0, sBb);
  STG_B(0, 1, sBb + 8192);
  STG_A(1, 0, sAb + 16384);
  STG_B(1, 1, sBb + 16384 + 8192);
  asm volatile("s_waitcnt vmcnt(4)" ::: "memory");
  BAR();
  SCHED0();

  for (int tt = 0; tt < 32; ++tt) {
    // ======== even tile t = 2*tt (cur = buf0, nxt = buf1) ========
    // P1: reads + stages BEFORE barrier; MFMA after
    READ_A(sAb);
    if (doB0) READ_B(sBb, bva);
    if (doB1) READ_B(sBb + 8192, bvb);
    STG_A(2 * tt + 1, 1, sAb + 16384 + 8192);
    STG_B(2 * tt + 1, 0, sBb + 16384);
    SCHED0();
    BAR();
    SCHED0();
    if (doB0) MFMA_Q(0, 0, bva);
    if (doB1) MFMA_Q(0, 1, bvb);
    // P2
    READ_A(sAb + 8192);
    if (tt < 31) {
      STG_A(2 * tt + 2, 0, sAb);
      STG_B(2 * tt + 2, 1, sBb + 8192);
    }
    if (tt < 31) {
      asm volatile("s_waitcnt vmcnt(4)" ::: "memory");
    } else {
      asm volatile("s_waitcnt vmcnt(0)" ::: "memory");
    }
    SCHED0();
    BAR();
    SCHED0();
    if (doB1) MFMA_Q(1, 1, bvb);
    if (doB0) MFMA_Q(1, 0, bva);

    // ======== odd tile t = 2*tt+1 (cur = buf1, nxt = buf0) ========
    READ_A(sAb + 16384);
    if (doB0) READ_B(sBb + 16384, bva);
    if (doB1) READ_B(sBb + 16384 + 8192, bvb);
    if (tt < 31) {
      STG_A(2 * tt + 2, 1, sAb + 8192);
      STG_B(2 * tt + 2, 0, sBb);
    }
    SCHED0();
    BAR();
    SCHED0();
    if (doB0) MFMA_Q(0, 0, bva);
    if (doB1) MFMA_Q(0, 1, bvb);
    // P2
    READ_A(sAb + 16384 + 8192);
    if (tt < 31) {
      STG_A(2 * tt + 3, 0, sAb + 16384);
      STG_B(2 * tt + 3, 1, sBb + 16384 + 8192);
    }
    if (tt < 31) {
      asm volatile("s_waitcnt vmcnt(4)" ::: "memory");
      SCHED0();
      BAR();
      SCHED0();
    }
    if (doB1) MFMA_Q(1, 1, bvb);
    if (doB0) MFMA_Q(1, 0, bva);
  }

  // ---- epilogue: C/D layout col=lane&15, row=(lane>>4)*4+reg ----
  const int r0 = tm * 256 + wr * 64 + sb * 4;
  const int c0 = tn * 256 + wc * 32 + fr;
#pragma unroll
  for (int n = 0; n < 4; ++n) {
    if (!isFull && (n >> 1) != nh) continue;   // half-job: own column half only
    const int col = c0 + (n >> 1) * 128 + (n & 1) * 16;
    const float bv = bias[col];
#pragma unroll
    for (int mi = 0; mi < 8; ++mi) {
      const int row = r0 + (mi >> 2) * 128 + (mi & 3) * 16;
#pragma unroll
      for (int jj = 0; jj < 4; ++jj)
        C[(size_t)(row + jj) * N_DIM + col] = acc[mi][n][jj] + bv;
    }
  }
}

extern "C" void kernel_launch(void* const* d_in, const int* in_sizes, int n_in,
                              void* d_out, int out_size, void* d_ws, size_t ws_size,
                              hipStream_t stream) {
  const float* x = (const float*)d_in[0];
  const int* qw = (const int*)d_in[1];
  const float* sc = (const float*)d_in[2];
  const float* zr = (const float*)d_in[3];
  const float* bs = (const float*)d_in[4];
  float* out = (float*)d_out;

  const size_t xb_bytes = (size_t)M_DIM * K_DIM * 2;
  const size_t wb_bytes = (size_t)N_DIM * K_DIM * 2;
  if (ws_size < xb_bytes + wb_bytes) return;

  unsigned short* xb = (unsigned short*)d_ws;
  unsigned short* wb = (unsigned short*)((char*)d_ws + xb_bytes);

  (void)hipFuncSetAttribute((const void*)gemm_kernel,
                            hipFuncAttributeMaxDynamicSharedMemorySize, 131072);

  prep_kernel<<<16384 + 22016, 256, 0, stream>>>((const float4*)x, (const int4*)qw, sc, zr,
                                                 (u16x8*)xb, (u16x8*)wb);
  gemm_kernel<<<1280 + 192, 512, 131072, stream>>>(xb, wb, bs, out);
}